// Round 1
// baseline (373.167 us; speedup 1.0000x reference)
//
#include <hip/hip_runtime.h>
#include <stdint.h>

// ---------------------------------------------------------------------------
// SimVQ: z_e (8192x512 f32), codebook (16384x512 f32), W (512x512 f32)
// eff = codebook @ W.T; idx[i] = argmin_k (||eff_k||^2 - 2 z_i.eff_k)
// z_q = eff[idx]; total_loss = 1.25 * mean((z_e - z_q)^2)
// out (f32): [z_q (4194304)] [loss (1)] [indices-as-float (8192)]
//
// eff GEMM: 3-limb f16 MFMA, 128^2 tiles (512 blocks, 2 blocks/CU); epilogue
// writes fp32 eff AND the pre-tiled 1-limb f16 BpT for the dist pass.
// Pass 1: approx scores via 1-limb f16 MFMA (K=512), per-32col-group minima.
// PERSISTENT version: 256 blocks (1/CU), each handles its 8 (mp,np) tiles
// (np fixed per block, mp stride-4) in ONE 64-step pipelined K-loop; the
// vmcnt(6) prefetch discipline flows across tile boundaries, and the
// min-reduce epilogue is split (mf0..3 / mf4..7) into MFMA shadow slots.
// Flag groups within margin of row best. Refine: exact fp32 on flagged.
// ---------------------------------------------------------------------------

#define N_ROWS 8192
#define DIM    512
#define K_CB   16384
#define TILE_F16 16384         // 256x64 f16 (32 KB)
#define HALF_F16 8192
#define KT_EFF 24              // eff GEMM: K'=1536
#define KT_D   8               // dist pass: K=512
#define PAN_D   ((size_t)KT_D * TILE_F16)
#define RMARGIN 4.0f

typedef _Float16 f16x8 __attribute__((ext_vector_type(8)));
typedef float f32x4 __attribute__((ext_vector_type(4)));

#define FENCE() asm volatile("" ::: "memory")
#define BARRIER() do { FENCE(); __builtin_amdgcn_s_barrier(); FENCE(); } while (0)
#define VMCNT(n) asm volatile("s_waitcnt vmcnt(" #n ")" ::: "memory")

__device__ __forceinline__ void gload_lds16(const void* g, void* l) {
  __builtin_amdgcn_global_load_lds(
      (const __attribute__((address_space(1))) uint32_t*)g,
      (__attribute__((address_space(3))) uint32_t*)l, 16, 0, 0);
}

// ----------------------- shared GEMM building blocks -----------------------

__device__ __forceinline__ void stage_half(const _Float16* src, _Float16* ldsb,
                                           int w, int lane) {
  const _Float16* s = src + w * 512 + lane * 8;
  _Float16* l = ldsb + w * 512;
  gload_lds16(s, l);
  gload_lds16(s + 4096, l + 4096);
}

template <int MQ>
__device__ __forceinline__ void read_a(const _Float16* At, int wr, int lh, int lq,
                                       f16x8 af[4][2]) {
#pragma unroll
  for (int m2 = 0; m2 < 4; ++m2) {
    const int row = wr * 128 + (MQ * 4 + m2) * 16 + lh;
    const int half = row >> 7, r = row & 127;
#pragma unroll
    for (int kk = 0; kk < 2; ++kk) {
      const int kblk = kk * 4 + lq;
      af[m2][kk] = *reinterpret_cast<const f16x8*>(
          &At[(((size_t)(half * 8 + kblk)) * 128 + r) * 8]);
    }
  }
}

template <int NQ>
__device__ __forceinline__ void read_b(const _Float16* Bt, int wc, int lh, int lq,
                                       f16x8 bf[4][2]) {
#pragma unroll
  for (int n2 = 0; n2 < 2; ++n2) {
    const int row = wc * 64 + (NQ * 2 + n2) * 16 + lh;
    const int half = row >> 7, r = row & 127;
#pragma unroll
    for (int kk = 0; kk < 2; ++kk) {
      const int kblk = kk * 4 + lq;
      bf[NQ * 2 + n2][kk] = *reinterpret_cast<const f16x8*>(
          &Bt[(((size_t)(half * 8 + kblk)) * 128 + r) * 8]);
    }
  }
}

template <int MQ, int NQ>
__device__ __forceinline__ void mfma_phase(const f16x8 af[4][2],
                                           const f16x8 bf[4][2],
                                           f32x4 acc[8][4]) {
  __builtin_amdgcn_s_setprio(1);
#pragma unroll
  for (int m2 = 0; m2 < 4; ++m2)
#pragma unroll
    for (int n2 = 0; n2 < 2; ++n2)
#pragma unroll
      for (int kk = 0; kk < 2; ++kk)
        acc[MQ * 4 + m2][NQ * 2 + n2] = __builtin_amdgcn_mfma_f32_16x16x32_f16(
            af[m2][kk], bf[NQ * 2 + n2][kk], acc[MQ * 4 + m2][NQ * 2 + n2], 0, 0, 0);
  __builtin_amdgcn_s_setprio(0);
}

// Half-epilogue for dist1: fold En, min-reduce across lh lanes, store group
// minima for rows mf = MFB..MFB+3, then zero those accumulators.
// All indices compile-time after unroll (MFB is a template constant).
template <int MFB>
__device__ __forceinline__ void epi_half(f32x4 (&acc)[8][4], const float (&en)[4],
                                         int mp, int np, int wr, int wc,
                                         int lh, int lq, float* __restrict__ gv) {
  const f32x4 fz = {};
#pragma unroll
  for (int mf2 = 0; mf2 < 4; ++mf2) {
    const int mf = MFB + mf2;
#pragma unroll
    for (int j = 0; j < 4; ++j) {
      float v0 = fmaf(-2.f, acc[mf][0][j], en[0]);
      v0 = fminf(v0, fmaf(-2.f, acc[mf][1][j], en[1]));
      float v1 = fmaf(-2.f, acc[mf][2][j], en[2]);
      v1 = fminf(v1, fmaf(-2.f, acc[mf][3][j], en[3]));
#pragma unroll
      for (int m = 1; m < 16; m <<= 1) {
        v0 = fminf(v0, __shfl_xor(v0, m, 64));
        v1 = fminf(v1, __shfl_xor(v1, m, 64));
      }
      if (lh == 0) {
        const int row = mp * 256 + wr * 128 + mf * 16 + lq * 4 + j;
        float* gp = &gv[(size_t)row * 512 + np * 8 + wc * 2];
        gp[0] = v0; gp[1] = v1;
      }
    }
#pragma unroll
    for (int nf = 0; nf < 4; ++nf) acc[mf][nf] = fz;
  }
}

// -------------------- limb splits into pre-tiled layout --------------------
// 3-limb: [panel][kt(24)][half][kblk(8)][row(128)][8]; limb group per kt/8.
__global__ __launch_bounds__(256) void split_tiled_kernel(
    const float* __restrict__ S, _Float16* __restrict__ T, int resid_limb) {
  const int b = blockIdx.x;
  const int mp = b / 48;
  const int r1 = b % 48;
  const int kt = r1 >> 1, half = r1 & 1;
  const int limb = kt >> 3;
  const int ksrc = (kt & 7) * 64;
  const bool resid = (limb == resid_limb);
  const int t = threadIdx.x;
  _Float16* dst = T + ((size_t)(mp * KT_EFF + kt) * 2 + half) * HALF_F16;
#pragma unroll
  for (int cc = 0; cc < 4; ++cc) {
    const int ci = cc * 256 + t;
    const int kblk = ci >> 7, row = ci & 127;
    const int m = mp * 256 + half * 128 + row;
    const float* src = &S[(size_t)m * DIM + ksrc + kblk * 8];
    float4 x0 = *reinterpret_cast<const float4*>(src);
    float4 x1 = *reinterpret_cast<const float4*>(src + 4);
    const float xs[8] = {x0.x, x0.y, x0.z, x0.w, x1.x, x1.y, x1.z, x1.w};
    f16x8 o;
    if (!resid) {
#pragma unroll
      for (int j = 0; j < 8; ++j) o[j] = (_Float16)xs[j];
    } else {
#pragma unroll
      for (int j = 0; j < 8; ++j) {
        _Float16 h = (_Float16)xs[j];
        o[j] = (_Float16)(xs[j] - (float)h);
      }
    }
    *reinterpret_cast<f16x8*>(&dst[(size_t)ci * 8]) = o;
  }
}

// 1-limb: [panel][kt(8)][half][kblk(8)][row(128)][8]  (for z_e -> ApT)
__global__ __launch_bounds__(256) void split1_kernel(
    const float* __restrict__ S, _Float16* __restrict__ T) {
  const int b = blockIdx.x;
  const int p = b >> 4;
  const int r1 = b & 15;
  const int kt = r1 >> 1, half = r1 & 1;
  const int ksrc = kt * 64;
  const int t = threadIdx.x;
  _Float16* dst = T + ((size_t)(p * KT_D + kt) * 2 + half) * HALF_F16;
#pragma unroll
  for (int cc = 0; cc < 4; ++cc) {
    const int ci = cc * 256 + t;
    const int kblk = ci >> 7, row = ci & 127;
    const int m = p * 256 + half * 128 + row;
    const float* src = &S[(size_t)m * DIM + ksrc + kblk * 8];
    float4 x0 = *reinterpret_cast<const float4*>(src);
    float4 x1 = *reinterpret_cast<const float4*>(src + 4);
    const float xs[8] = {x0.x, x0.y, x0.z, x0.w, x1.x, x1.y, x1.z, x1.w};
    f16x8 o;
#pragma unroll
    for (int j = 0; j < 8; ++j) o[j] = (_Float16)xs[j];
    *reinterpret_cast<f16x8*>(&dst[(size_t)ci * 8]) = o;
  }
}

// ----------------- eff GEMM: 128^2 tiles, fused f16 emission ---------------
// Block: 256 thr, 4 waves (2x2 of 64x64), BK=64, double-buffered 64 KB LDS.
// Epilogue writes fp32 eff AND pre-tiled 1-limb BpT.
__global__ __launch_bounds__(256) void effgemm128_kernel(
    const _Float16* __restrict__ CpT, const _Float16* __restrict__ WpT,
    float* __restrict__ eff, _Float16* __restrict__ BpT) {
  __shared__ __align__(16) _Float16 lbuf[2][2][HALF_F16];  // 64 KB
  const int tid = threadIdx.x;
  const int w = tid >> 6, lane = tid & 63;
  const int lh = lane & 15, lq = lane >> 4;
  const int wr = w >> 1, wc = w & 1;
  const int bid = blockIdx.x;
  const int nb = bid & 3, mh = bid >> 2;       // mh: 128-row half (0..127)
  const int pA = mh >> 1, hA = mh & 1;
  const int pB = nb >> 1, hB = nb & 1;
  f32x4 acc[4][4] = {};

  // stage one kt (A-half + B-half) into buf
  auto stage = [&](int kt, int buf) {
    const _Float16* a = CpT + (((size_t)pA * KT_EFF + kt) * 2 + hA) * HALF_F16;
    const _Float16* b = WpT + (((size_t)pB * KT_EFF + kt) * 2 + hB) * HALF_F16;
#pragma unroll
    for (int i = 0; i < 4; ++i) {
      const int off = i * 2048 + w * 512;
      gload_lds16(a + off + lane * 8, &lbuf[buf][0][off]);
      gload_lds16(b + off + lane * 8, &lbuf[buf][1][off]);
    }
  };

  stage(0, 0);
  for (int kt = 0; kt < KT_EFF; ++kt) {
    __syncthreads();
    if (kt + 1 < KT_EFF) stage(kt + 1, (kt + 1) & 1);
    const _Float16* At = &lbuf[kt & 1][0][0];
    const _Float16* Bt = &lbuf[kt & 1][1][0];
    f16x8 af[4][2], bf[4][2];
#pragma unroll
    for (int mf = 0; mf < 4; ++mf) {
      const int r = wr * 64 + mf * 16 + lh;
#pragma unroll
      for (int kk = 0; kk < 2; ++kk)
        af[mf][kk] = *reinterpret_cast<const f16x8*>(
            &At[((kk * 4 + lq) * 128 + r) * 8]);
    }
#pragma unroll
    for (int nf = 0; nf < 4; ++nf) {
      const int r = wc * 64 + nf * 16 + lh;
#pragma unroll
      for (int kk = 0; kk < 2; ++kk)
        bf[nf][kk] = *reinterpret_cast<const f16x8*>(
            &Bt[((kk * 4 + lq) * 128 + r) * 8]);
    }
    __builtin_amdgcn_s_setprio(1);
#pragma unroll
    for (int mf = 0; mf < 4; ++mf)
#pragma unroll
      for (int nf = 0; nf < 4; ++nf)
#pragma unroll
        for (int kk = 0; kk < 2; ++kk)
          acc[mf][nf] = __builtin_amdgcn_mfma_f32_16x16x32_f16(
              af[mf][kk], bf[nf][kk], acc[mf][nf], 0, 0, 0);
    __builtin_amdgcn_s_setprio(0);
  }

#pragma unroll
  for (int mf = 0; mf < 4; ++mf)
#pragma unroll
    for (int nf = 0; nf < 4; ++nf)
#pragma unroll
      for (int j = 0; j < 4; ++j) {
        const int rl = wr * 64 + mf * 16 + lq * 4 + j;
        const int cl = wc * 64 + nf * 16 + lh;
        const int row = mh * 128 + rl;
        const int col = nb * 128 + cl;
        const float v = acc[mf][nf][j];
        eff[(size_t)row * DIM + col] = v;
        const int ktd = col >> 6, kblk = (col >> 3) & 7, ce = col & 7;
        BpT[((((size_t)(row >> 8) * KT_D + ktd) * 2 + ((row >> 7) & 1)) * 8 + kblk)
                * 1024 + (row & 127) * 8 + ce] = (_Float16)v;
      }
}

__global__ __launch_bounds__(256) void effnorm_kernel(
    const float* __restrict__ E, float* __restrict__ En) {
  const int w = threadIdx.x >> 6;
  const int lane = threadIdx.x & 63;
  const int row = blockIdx.x * 4 + w;
  const float* er = &E[(size_t)row * DIM];
  float s = 0.f;
#pragma unroll
  for (int k = 0; k < DIM / 64; ++k) {
    float v = er[lane + k * 64];
    s = fmaf(v, v, s);
  }
#pragma unroll
  for (int o = 32; o; o >>= 1) s += __shfl_down(s, o, 64);
  if (lane == 0) En[row] = s;
}

// --------------------- dist pass 1: persistent 8-tile blocks ---------------
// Grid 256 (1 block/CU). Block p: xcd=p&7, q=p>>3; np = xcd*8+(q&7) FIXED,
// mp(r) = (q>>3) + 4r for r=0..7 (identical tile set to the old 2048-block
// dispatch, so per-XCD L2 residency of the B octet is preserved).
// One continuous 64-step K-loop; prefetch pipeline never drains between
// tiles. Epilogue split: mf0..3 after mfma<1,1> of tile-final step, mf4..7
// after mfma<0,0> of the next tile's first step (both data-independent of
// in-flight MFMAs). Store-emitting steps use vmcnt(38) (=32 stores + 6
// prefetch loads) so counted waits never stall on store retire; the next
// normal step's vmcnt(6) drains stores for free.
__global__ __launch_bounds__(512) void dist1_kernel(
    const _Float16* __restrict__ ApT, const _Float16* __restrict__ BpT,
    const float* __restrict__ En, float* __restrict__ gv) {
  __shared__ __align__(16) _Float16 lds[4][TILE_F16];
  const int tid = threadIdx.x;
  const int w = tid >> 6, lane = tid & 63;
  const int lh = lane & 15, lq = lane >> 4;
  const int wr = w >> 2, wc = w & 3;
  const int p = blockIdx.x;
  const int xcd = p & 7, q = p >> 3;
  const int np = xcd * 8 + (q & 7);
  const int mp0 = q >> 3;                       // mp(r) = mp0 + 4*r
  const _Float16* Ab = ApT + (size_t)mp0 * PAN_D;
  const _Float16* Bb = BpT + (size_t)np * PAN_D;

  float en[4];
#pragma unroll
  for (int nf = 0; nf < 4; ++nf)
    en[nf] = En[np * 256 + wc * 64 + nf * 16 + lh];

  f32x4 acc[8][4] = {};
  f16x8 af[4][2], bf[4][2];

  auto Aoff = [&](int g) -> const _Float16* {
    return Ab + (size_t)(g >> 3) * (4 * PAN_D) + (size_t)(g & 7) * TILE_F16;
  };

  const int GT = 64;  // 8 tiles x 8 K-steps
  // prologue: A(0) h1+h2, B(0) h1+h2, B(1) h1+h2, A(1) h1
  stage_half(Aoff(0), &lds[0][0], w, lane);
  stage_half(Aoff(0) + HALF_F16, &lds[0][HALF_F16], w, lane);
  stage_half(Bb, &lds[1][0], w, lane);
  stage_half(Bb + HALF_F16, &lds[1][HALF_F16], w, lane);
  stage_half(Bb + TILE_F16, &lds[3][0], w, lane);
  stage_half(Bb + TILE_F16 + HALF_F16, &lds[3][HALF_F16], w, lane);
  stage_half(Aoff(1), &lds[2][0], w, lane);
  VMCNT(6);
  BARRIER();

  for (int t = 0; t < GT; ++t) {
    const int s = t & 1;
    const _Float16* At = &lds[s * 2 + 0][0];
    const _Float16* Bt = &lds[s * 2 + 1][0];
    const bool lastk = (t & 7) == 7;            // tile-final K-step
    const bool firstk = ((t & 7) == 0) && (t > 0);  // tile-first (not global)
    read_a<0>(At, wr, lh, lq, af);
    read_b<0>(Bt, wc, lh, lq, bf);
    if (t + 1 < GT)
      stage_half(Aoff(t + 1) + HALF_F16, &lds[(s ^ 1) * 2][HALF_F16], w, lane);
    BARRIER();
    mfma_phase<0, 0>(af, bf, acc);              // writes mf0..3, nf0..1
    if (firstk)                                  // prev tile, acc[4..7] idle
      epi_half<4>(acc, en, mp0 + 4 * ((t >> 3) - 1), np, wr, wc, lh, lq, gv);
    BARRIER();
    read_b<1>(Bt, wc, lh, lq, bf);
    BARRIER();
    mfma_phase<0, 1>(af, bf, acc);              // writes mf0..3, nf2..3
    BARRIER();
    read_a<1>(At, wr, lh, lq, af);
    if (t + 2 < GT)
      stage_half(Bb + (size_t)((t + 2) & 7) * TILE_F16, &lds[s * 2 + 1][0],
                 w, lane);
    BARRIER();
    mfma_phase<1, 1>(af, bf, acc);              // writes mf4..7, nf2..3
    if (lastk)                                   // this tile, acc[0..3] done
      epi_half<0>(acc, en, mp0 + 4 * (t >> 3), np, wr, wc, lh, lq, gv);
    BARRIER();
    if (t + 2 < GT) {
      stage_half(Bb + (size_t)((t + 2) & 7) * TILE_F16 + HALF_F16,
                 &lds[s * 2 + 1][HALF_F16], w, lane);
      stage_half(Aoff(t + 2), &lds[s * 2][0], w, lane);
    }
    BARRIER();
    mfma_phase<1, 0>(af, bf, acc);              // writes mf4..7, nf0..1
    if (t == GT - 2) { VMCNT(0); }
    else if (lastk || firstk) { VMCNT(38); }
    else { VMCNT(6); }
    BARRIER();
  }
  // final tile's mf4..7
  epi_half<4>(acc, en, mp0 + 4 * 7, np, wr, wc, lh, lq, gv);
}

// ------------------------------- flag pass ---------------------------------
__global__ __launch_bounds__(256) void flag_kernel(
    const float* __restrict__ gv, int* __restrict__ fcnt,
    unsigned short* __restrict__ flist) {
  const int t = threadIdx.x;
  const int w = t >> 6, lane = t & 63;
  const int row = blockIdx.x * 4 + w;
  float v[8];
#pragma unroll
  for (int i = 0; i < 8; ++i) v[i] = gv[(size_t)row * 512 + i * 64 + lane];
  float A = v[0];
#pragma unroll
  for (int i = 1; i < 8; ++i) A = fminf(A, v[i]);
#pragma unroll
  for (int m = 1; m < 64; m <<= 1) A = fminf(A, __shfl_xor(A, m, 64));
  __shared__ int cnt[4];
  __shared__ unsigned short lst[4][64];
  if (lane == 0) cnt[w] = 0;
  __syncthreads();
  const float thr = A + RMARGIN;
#pragma unroll
  for (int i = 0; i < 8; ++i) {
    if (v[i] <= thr) {
      int p = atomicAdd(&cnt[w], 1);
      if (p < 64) lst[w][p] = (unsigned short)(i * 64 + lane);
    }
  }
  __syncthreads();
  const int cn = cnt[w];
  if (lane == 0) fcnt[row] = (cn > 64) ? -1 : cn;
  if (lane < cn && lane < 64) flist[(size_t)row * 64 + lane] = lst[w][lane];
}

// ---------------- refine (exact fp32) + gather z_q + loss ------------------
__global__ __launch_bounds__(256) void refine_kernel(
    const float* __restrict__ Z, const float* __restrict__ E,
    const float* __restrict__ En, const int* __restrict__ fcnt,
    const unsigned short* __restrict__ flist, float* __restrict__ zq,
    float* __restrict__ out_idx, float* __restrict__ ploss) {
  const int row = blockIdx.x;
  const int t = threadIdx.x;
  __shared__ float zrow[512];
  __shared__ unsigned short glist[512];
  __shared__ float pacc[256];
  __shared__ int sidx;
  __shared__ float wsum[4];
  if (t < 128)
    ((float4*)zrow)[t] = ((const float4*)(Z + (size_t)row * 512))[t];
  const int cr = fcnt[row];
  int ncand;
  if (cr < 0) {
    glist[t] = (unsigned short)t;
    glist[t + 256] = (unsigned short)(t + 256);
    ncand = 512;
  } else {
    ncand = cr;
    if (t < cr) glist[t] = flist[(size_t)row * 64 + t];
  }
  __syncthreads();

  float bv = 3.0e38f;
  int bi = 2147483647;
  const int col32 = t & 31, sl = t >> 5;
  for (int q = 0; q < ncand; ++q) {
    const int g = glist[q];
    const int cc = g * 32 + col32;
    const float4* er = (const float4*)(E + (size_t)cc * 512 + sl * 64);
    float p = 0.f;
#pragma unroll
    for (int dd = 0; dd < 16; ++dd) {
      float4 e4 = er[dd];
      const float* zz = &zrow[sl * 64 + dd * 4];
      p = fmaf(zz[0], e4.x, p); p = fmaf(zz[1], e4.y, p);
      p = fmaf(zz[2], e4.z, p); p = fmaf(zz[3], e4.w, p);
    }
    pacc[sl * 32 + col32] = p;
    __syncthreads();
    if (t < 32) {
      float dot = pacc[t];
#pragma unroll
      for (int s2 = 1; s2 < 8; ++s2) dot += pacc[s2 * 32 + t];
      const int ci = g * 32 + t;
      const float v = fmaf(-2.f, dot, En[ci]);
      if (v < bv || (v == bv && ci < bi)) { bv = v; bi = ci; }
    }
    __syncthreads();
  }
  if (t < 64) {
#pragma unroll
    for (int m = 1; m < 64; m <<= 1) {
      const float v2 = __shfl_xor(bv, m, 64);
      const int i2 = __shfl_xor(bi, m, 64);
      if (v2 < bv || (v2 == bv && i2 < bi)) { bv = v2; bi = i2; }
    }
    if (t == 0) sidx = bi;
  }
  __syncthreads();
  const int idx = sidx;

  float s = 0.f;
  const float* erow = E + (size_t)idx * 512;
#pragma unroll
  for (int d0 = 0; d0 < 512; d0 += 256) {
    const int d = d0 + t;
    const float e = erow[d];
    const float z = zrow[d];
    zq[(size_t)row * 512 + d] = e;
    const float df = z - e;
    s = fmaf(df, df, s);
  }
#pragma unroll
  for (int o = 32; o; o >>= 1) s += __shfl_down(s, o, 64);
  if ((t & 63) == 0) wsum[t >> 6] = s;
  __syncthreads();
  if (t == 0) {
    ploss[row] = wsum[0] + wsum[1] + wsum[2] + wsum[3];
    out_idx[row] = (float)idx;
  }
}

__global__ __launch_bounds__(256) void loss_final_kernel(
    const float* __restrict__ ploss, float* __restrict__ out_loss) {
  const int t = threadIdx.x;
  double s = 0.0;
  for (int i = t; i < N_ROWS; i += 256) s += (double)ploss[i];
#pragma unroll
  for (int o = 32; o; o >>= 1) s += __shfl_down(s, o, 64);
  __shared__ double ds[4];
  if ((t & 63) == 0) ds[t >> 6] = s;
  __syncthreads();
  if (t == 0) {
    double tot = ds[0] + ds[1] + ds[2] + ds[3];
    out_loss[0] = (float)(1.25 * tot / ((double)N_ROWS * (double)DIM));
  }
}

// --------------------------------- launch ----------------------------------

extern "C" void kernel_launch(void* const* d_in, const int* in_sizes, int n_in,
                              void* d_out, int out_size, void* d_ws, size_t ws_size,
                              hipStream_t stream) {
  const float* z_e      = (const float*)d_in[0];
  const float* codebook = (const float*)d_in[1];
  const float* W        = (const float*)d_in[2];
  float* out = (float*)d_out;
  char* ws = (char*)d_ws;

  float*          eff     = (float*)(ws);                 // 33,554,432
  float*          effnorm = (float*)(ws + 33554432);      // 65,536
  _Float16*       WpT     = (_Float16*)(ws + 33619968);   // 1,572,864
  int*            fcnt    = (int*)(ws + 35192832);        // 32,768
  unsigned short* flist   = (unsigned short*)(ws + 35225600); // 1,048,576
  float*          ploss   = (float*)(ws + 36274176);      // 32,768
  // CpT region [36,306,944 .. 86,638,592): dead after effgemm; gv/ApT overlay
  _Float16*       CpT     = (_Float16*)(ws + 36306944);   // 50,331,648
  float*          gv      = (float*)(ws + 36306944);      // 16,777,216
  _Float16*       ApT     = (_Float16*)(ws + 53084160);   // 8,388,608
  _Float16*       BpT     = (_Float16*)(ws + 86638592);   // 16,777,216 (to 103,415,808)

  float* out_zq   = out;
  float* out_loss = out + (size_t)N_ROWS * DIM;
  float* out_idx  = out + (size_t)N_ROWS * DIM + 1;

  // 1) 3-limb pre-tiled splits for eff GEMM
  split_tiled_kernel<<<64 * 48, 256, 0, stream>>>(codebook, CpT, 2);
  split_tiled_kernel<<<2 * 48, 256, 0, stream>>>(W, WpT, 1);
  // 2) eff = codebook @ W.T (3-limb f16 MFMA, 128^2 tiles) + fused BpT f16
  effgemm128_kernel<<<512, 256, 0, stream>>>(CpT, WpT, eff, BpT);
  // 3) ||eff_k||^2
  effnorm_kernel<<<K_CB / 4, 256, 0, stream>>>(eff, effnorm);
  // 4) 1-limb pre-tiled split of z (overlays dead CpT region)
  split1_kernel<<<32 * 16, 256, 0, stream>>>(z_e, ApT);
  // 5) approx distance pass + per-32col-group minima (persistent, 1 block/CU)
  dist1_kernel<<<256, 512, 0, stream>>>(ApT, BpT, effnorm, gv);
  // 6) flag candidate groups
  flag_kernel<<<N_ROWS / 4, 256, 0, stream>>>(gv, fcnt, flist);
  // 7) exact refine + gather z_q + loss partials
  refine_kernel<<<N_ROWS, 256, 0, stream>>>(z_e, eff, effnorm, fcnt, flist,
                                            out_zq, out_idx, ploss);
  // 8) final loss
  loss_final_kernel<<<1, 256, 0, stream>>>(ploss, out_loss);
}